// Round 1
// baseline (360.957 us; speedup 1.0000x reference)
//
#include <hip/hip_runtime.h>
#include <hip/hip_bf16.h>

typedef __bf16 bf16x8 __attribute__((ext_vector_type(8)));
typedef __bf16 bf16x4 __attribute__((ext_vector_type(4)));
typedef __bf16 bf16x2 __attribute__((ext_vector_type(2)));
typedef float  f32x4  __attribute__((ext_vector_type(4)));

#define NB   4
#define C_   256
#define CI_  128
#define NSP  8192   // 8*32*32
#define NKV  2048   // 8*16*16

// ---------------- kernel 0: weight prep (bf16 cast, BN fold) ----------------
__global__ __launch_bounds__(256) void prep_kernel(
    const float* __restrict__ g_w,  const float* __restrict__ g_b,
    const float* __restrict__ th_w, const float* __restrict__ th_b,
    const float* __restrict__ ph_w, const float* __restrict__ ph_b,
    const float* __restrict__ w_w,  const float* __restrict__ w_b,
    const float* __restrict__ bn_g, const float* __restrict__ bn_be,
    const float* __restrict__ bn_m, const float* __restrict__ bn_v,
    __bf16* __restrict__ w_all, __bf16* __restrict__ w2,
    float* __restrict__ b_all, float* __restrict__ bnA, float* __restrict__ bnB)
{
    int idx = blockIdx.x * 256 + threadIdx.x;
    if (idx < 98304) {                       // w_all: [theta;phi;g] 384x256
        int o = idx >> 8, c = idx & 255;
        float v;
        if (o < 128)      v = th_w[o*256 + c];
        else if (o < 256) v = ph_w[(o-128)*256 + c];
        else              v = g_w[(o-256)*256 + c];
        w_all[idx] = (__bf16)v;
    } else if (idx < 131072) {               // w2: 256x128
        int j = idx - 98304;
        w2[j] = (__bf16)w_w[j];
    } else if (idx < 131456) {               // b_all: 384
        int k = idx - 131072;
        float v;
        if (k < 128) v = th_b[k]; else if (k < 256) v = ph_b[k-128]; else v = g_b[k-256];
        b_all[k] = v;
    } else if (idx < 131712) {               // BN fold (+w_b): 256
        int m = idx - 131456;
        float sc = bn_g[m] * rsqrtf(bn_v[m] + 1e-5f);
        bnA[m] = sc;
        bnB[m] = w_b[m]*sc + bn_be[m] - bn_m[m]*sc;
    }
}

// ---------------- kernel 1: fused 3-way projection + (1,2,2) maxpool ----------------
// Per block: batch b, 64 consecutive spatial positions (2 h-rows x 32 w), all 384 outputs.
// D[n][o] = sum_c x[c][n] * w_all[o][c]   via mfma_f32_16x16x32_bf16
// C-layout: row n = (lane>>4)*4+i, col o = lane&15 -> all 4 elems of each 2x2 pool
// window live in one lane (i-pairs horizontal, nf/nf+2 vertical).
__global__ __launch_bounds__(256, 2) void proj_kernel(
    const float* __restrict__ x, const __bf16* __restrict__ w_all,
    const float* __restrict__ b_all,
    __bf16* __restrict__ Q, __bf16* __restrict__ K, __bf16* __restrict__ VT)
{
    const int b    = blockIdx.x >> 7;
    const int tile = blockIdx.x & 127;
    const int n0   = tile * 64;
    const int w    = threadIdx.x >> 6;
    const int lane = threadIdx.x & 63;
    const int lq   = lane & 15;
    const int g    = lane >> 4;

    const float* xb = x + b * (C_ * NSP);

    f32x4 acc[4][6];
    #pragma unroll
    for (int a = 0; a < 4; ++a)
        #pragma unroll
        for (int o = 0; o < 6; ++o) acc[a][o] = (f32x4){0.f,0.f,0.f,0.f};

    #pragma unroll 1
    for (int ck = 0; ck < 8; ++ck) {
        const int cbase = ck*32 + g*8;
        bf16x8 afr[4];
        #pragma unroll
        for (int nf = 0; nf < 4; ++nf) {
            const int n = n0 + nf*16 + lq;
            const float* xp = xb + cbase*NSP + n;
            bf16x8 v;
            #pragma unroll
            for (int e = 0; e < 8; ++e) v[e] = (__bf16)xp[e*NSP];
            afr[nf] = v;
        }
        #pragma unroll
        for (int oi = 0; oi < 6; ++oi) {
            const int orow = (w*6 + oi)*16 + lq;
            bf16x8 bfr = *(const bf16x8*)(w_all + orow*256 + cbase);
            #pragma unroll
            for (int nf = 0; nf < 4; ++nf)
                acc[nf][oi] = __builtin_amdgcn_mfma_f32_16x16x32_bf16(afr[nf], bfr, acc[nf][oi], 0,0,0);
        }
    }

    // epilogue: bias, then route theta->Q, phi->pool->K, g->pool->VT
    const int t  = n0 >> 10;
    const int h0 = (n0 & 1023) >> 5;             // even
    const int kvrow0 = t*256 + (h0 >> 1)*16;

    #pragma unroll
    for (int oi = 0; oi < 6; ++oi) {
        const int ocol = (w*6 + oi)*16 + lq;
        const float bias = b_all[ocol];
        float v[4][4];
        #pragma unroll
        for (int nf = 0; nf < 4; ++nf)
            #pragma unroll
            for (int i = 0; i < 4; ++i) v[nf][i] = acc[nf][oi][i] + bias;

        const int seg = ocol >> 7;
        const int ol  = ocol & 127;
        if (seg == 0) {                      // theta -> Q[b][n][ol]
            #pragma unroll
            for (int nf = 0; nf < 4; ++nf)
                #pragma unroll
                for (int i = 0; i < 4; ++i) {
                    int n = n0 + nf*16 + g*4 + i;
                    Q[(b*NSP + n)*CI_ + ol] = (__bf16)v[nf][i];
                }
        } else if (seg == 1) {               // phi -> pool -> K[b][nkv][ol]
            #pragma unroll
            for (int nfp = 0; nfp < 2; ++nfp)
                #pragma unroll
                for (int j = 0; j < 2; ++j) {
                    float pv = fmaxf(fmaxf(v[nfp][2*j], v[nfp][2*j+1]),
                                     fmaxf(v[nfp+2][2*j], v[nfp+2][2*j+1]));
                    int wp = nfp*8 + g*2 + j;
                    K[(b*NKV + kvrow0 + wp)*CI_ + ol] = (__bf16)pv;
                }
        } else {                             // g -> pool -> VT[b][ol][nkv]
            #pragma unroll
            for (int nfp = 0; nfp < 2; ++nfp) {
                bf16x2 pk;
                #pragma unroll
                for (int j = 0; j < 2; ++j) {
                    float pv = fmaxf(fmaxf(v[nfp][2*j], v[nfp][2*j+1]),
                                     fmaxf(v[nfp+2][2*j], v[nfp+2][2*j+1]));
                    pk[j] = (__bf16)pv;
                }
                int wp = nfp*8 + g*2;        // j=0,1 consecutive -> 4B store
                *(bf16x2*)(VT + (b*CI_ + ol)*NKV + kvrow0 + wp) = pk;
            }
        }
    }
}

// ---------------- kernel 2: flash attention (swapped-operand, per-wave q-tile of 16) ----------------
__global__ __launch_bounds__(256, 2) void attn_kernel(
    const __bf16* __restrict__ Q, const __bf16* __restrict__ K,
    const __bf16* __restrict__ VT, __bf16* __restrict__ yy)
{
    __shared__ __bf16 plds[4][16][40];       // per-wave P buffer, 80B row stride
    const int b    = blockIdx.x >> 7;
    const int qt   = blockIdx.x & 127;
    const int w    = threadIdx.x >> 6;
    const int lane = threadIdx.x & 63;
    const int lq   = lane & 15;
    const int g    = lane >> 4;
    const int q0   = qt*64 + w*16;

    // Q fragments (B-operand: col q = lane&15, k = d)
    bf16x8 qf[4];
    const __bf16* qrow = Q + (size_t)(b*NSP + q0 + lq)*CI_;
    #pragma unroll
    for (int kk = 0; kk < 4; ++kk) qf[kk] = *(const bf16x8*)(qrow + kk*32 + g*8);

    float m_run = -1e30f, l_run = 0.f;
    f32x4 oacc[8];
    #pragma unroll
    for (int d = 0; d < 8; ++d) oacc[d] = (f32x4){0.f,0.f,0.f,0.f};

    const __bf16* Kb = K  + (size_t)b*NKV*CI_;
    const __bf16* Vb = VT + (size_t)b*CI_*NKV;
    __bf16* pw = &plds[w][0][0];
    const float LOG2E = 1.4426950408889634f;

    for (int kv0 = 0; kv0 < NKV; kv0 += 32) {
        // f^T[n][q] = sum_d K[n][d] Q[q][d]
        f32x4 facc[2] = {(f32x4){0.f,0.f,0.f,0.f}, (f32x4){0.f,0.f,0.f,0.f}};
        #pragma unroll
        for (int kk = 0; kk < 4; ++kk) {
            #pragma unroll
            for (int nf = 0; nf < 2; ++nf) {
                bf16x8 kf = *(const bf16x8*)(Kb + (size_t)(kv0 + nf*16 + lq)*CI_ + kk*32 + g*8);
                facc[nf] = __builtin_amdgcn_mfma_f32_16x16x32_bf16(kf, qf[kk], facc[nf], 0,0,0);
            }
        }
        // online softmax; lane holds 8 n-values for its q = lane&15
        float mt = facc[0][0];
        #pragma unroll
        for (int i = 1; i < 4; ++i) mt = fmaxf(mt, facc[0][i]);
        #pragma unroll
        for (int i = 0; i < 4; ++i) mt = fmaxf(mt, facc[1][i]);
        mt = fmaxf(mt, __shfl_xor(mt, 16, 64));
        mt = fmaxf(mt, __shfl_xor(mt, 32, 64));
        float mnew = fmaxf(m_run, mt);
        float corr = __builtin_amdgcn_exp2f((m_run - mnew) * LOG2E);
        float p[8], ps = 0.f;
        #pragma unroll
        for (int nf = 0; nf < 2; ++nf)
            #pragma unroll
            for (int i = 0; i < 4; ++i) {
                float e = __builtin_amdgcn_exp2f((facc[nf][i] - mnew) * LOG2E);
                p[nf*4 + i] = e; ps += e;
            }
        ps += __shfl_xor(ps, 16, 64);
        ps += __shfl_xor(ps, 32, 64);
        l_run = l_run * corr + ps;
        m_run = mnew;
        #pragma unroll
        for (int d = 0; d < 8; ++d) {
            oacc[d][0] *= corr; oacc[d][1] *= corr; oacc[d][2] *= corr; oacc[d][3] *= corr;
        }
        // P (lane-local rows) -> LDS, re-fragment for PV
        #pragma unroll
        for (int nf = 0; nf < 2; ++nf) {
            bf16x4 pk;
            #pragma unroll
            for (int i = 0; i < 4; ++i) pk[i] = (__bf16)p[nf*4 + i];
            *(bf16x4*)(pw + lq*40 + nf*16 + g*4) = pk;
        }
        asm volatile("s_waitcnt lgkmcnt(0)" ::: "memory");
        __builtin_amdgcn_sched_barrier(0);
        bf16x8 pb = *(const bf16x8*)(pw + lq*40 + g*8);
        // yy^T[d][q] += VT[d][n] * P^T[n][q]
        #pragma unroll
        for (int df = 0; df < 8; ++df) {
            bf16x8 vf = *(const bf16x8*)(Vb + (size_t)(df*16 + lq)*NKV + kv0 + g*8);
            oacc[df] = __builtin_amdgcn_mfma_f32_16x16x32_bf16(vf, pb, oacc[df], 0,0,0);
        }
    }

    float inv = 1.f / l_run;
    __bf16* yrow = yy + (size_t)(b*NSP + q0 + lq)*CI_;
    #pragma unroll
    for (int df = 0; df < 8; ++df) {
        bf16x4 ov;
        #pragma unroll
        for (int i = 0; i < 4; ++i) ov[i] = (__bf16)(oacc[df][i] * inv);
        *(bf16x4*)(yrow + df*16 + g*4) = ov;
    }
}

// ---------------- kernel 3: out-proj + BN + residual ----------------
// wy[co][n] = sum_d w2[co][d] * yy[n][d];  out = wy*bnA[co] + bnB[co] + x
__global__ __launch_bounds__(256, 2) void out_kernel(
    const __bf16* __restrict__ yy, const __bf16* __restrict__ w2,
    const float* __restrict__ bnA, const float* __restrict__ bnB,
    const float* __restrict__ x, float* __restrict__ out)
{
    const int b    = blockIdx.x >> 7;
    const int tile = blockIdx.x & 127;
    const int n0   = tile * 64;
    const int w    = threadIdx.x >> 6;
    const int lane = threadIdx.x & 63;
    const int lq   = lane & 15;
    const int g    = lane >> 4;

    f32x4 acc[4][4];   // [cof][nf]
    #pragma unroll
    for (int a = 0; a < 4; ++a)
        #pragma unroll
        for (int o = 0; o < 4; ++o) acc[a][o] = (f32x4){0.f,0.f,0.f,0.f};

    #pragma unroll
    for (int kk = 0; kk < 4; ++kk) {
        bf16x8 bfr[4];
        #pragma unroll
        for (int nf = 0; nf < 4; ++nf)
            bfr[nf] = *(const bf16x8*)(yy + (size_t)(b*NSP + n0 + nf*16 + lq)*CI_ + kk*32 + g*8);
        #pragma unroll
        for (int cf = 0; cf < 4; ++cf) {
            const int corow = (w*4 + cf)*16 + lq;
            bf16x8 afr = *(const bf16x8*)(w2 + corow*CI_ + kk*32 + g*8);
            #pragma unroll
            for (int nf = 0; nf < 4; ++nf)
                acc[cf][nf] = __builtin_amdgcn_mfma_f32_16x16x32_bf16(afr, bfr[nf], acc[cf][nf], 0,0,0);
        }
    }

    #pragma unroll
    for (int cf = 0; cf < 4; ++cf) {
        #pragma unroll
        for (int i = 0; i < 4; ++i) {
            int co = (w*4 + cf)*16 + g*4 + i;
            float A = bnA[co], Bv = bnB[co];
            #pragma unroll
            for (int nf = 0; nf < 4; ++nf) {
                int n = n0 + nf*16 + lq;
                size_t idx = (size_t)(b*C_ + co)*NSP + n;
                out[idx] = acc[cf][nf][i]*A + Bv + x[idx];
            }
        }
    }
}

// ---------------- launcher ----------------
extern "C" void kernel_launch(void* const* d_in, const int* in_sizes, int n_in,
                              void* d_out, int out_size, void* d_ws, size_t ws_size,
                              hipStream_t stream)
{
    const float* x    = (const float*)d_in[0];
    const float* g_w  = (const float*)d_in[1];
    const float* g_b  = (const float*)d_in[2];
    const float* th_w = (const float*)d_in[3];
    const float* th_b = (const float*)d_in[4];
    const float* ph_w = (const float*)d_in[5];
    const float* ph_b = (const float*)d_in[6];
    const float* w_w  = (const float*)d_in[7];
    const float* w_b  = (const float*)d_in[8];
    const float* bn_g = (const float*)d_in[9];
    const float* bn_be= (const float*)d_in[10];
    const float* bn_m = (const float*)d_in[11];
    const float* bn_v = (const float*)d_in[12];

    char* ws = (char*)d_ws;
    size_t off = 0;
    auto alloc = [&](size_t bytes) -> void* {
        void* p = ws + off;
        off += (bytes + 255) & ~(size_t)255;
        return p;
    };
    __bf16* w_all = (__bf16*)alloc(384*256*2);
    __bf16* w2    = (__bf16*)alloc(256*128*2);
    float*  b_all = (float*) alloc(384*4);
    float*  bnA   = (float*) alloc(256*4);
    float*  bnB   = (float*) alloc(256*4);
    __bf16* Qb    = (__bf16*)alloc((size_t)NB*NSP*CI_*2);
    __bf16* Kb    = (__bf16*)alloc((size_t)NB*NKV*CI_*2);
    __bf16* Vt    = (__bf16*)alloc((size_t)NB*CI_*NKV*2);
    __bf16* yyb   = (__bf16*)alloc((size_t)NB*NSP*CI_*2);

    prep_kernel<<<515, 256, 0, stream>>>(g_w, g_b, th_w, th_b, ph_w, ph_b, w_w, w_b,
                                         bn_g, bn_be, bn_m, bn_v,
                                         w_all, w2, b_all, bnA, bnB);
    proj_kernel<<<512, 256, 0, stream>>>(x, w_all, b_all, Qb, Kb, Vt);
    attn_kernel<<<512, 256, 0, stream>>>(Qb, Kb, Vt, yyb);
    out_kernel <<<512, 256, 0, stream>>>(yyb, w2, bnA, bnB, x, (float*)d_out);
}